// Round 14
// baseline (454.077 us; speedup 1.0000x reference)
//
#include <hip/hip_runtime.h>
#include <hip/hip_bf16.h>

#define B_ 2
#define S_ 2048
#define DM 2048
#define H_ 16
#define DH 128
#define NBLK 32
#define NKEEP 18
#define BH (B_ * H_)

typedef __attribute__((ext_vector_type(8))) short short8;
typedef __attribute__((ext_vector_type(8))) _Float16 f16x8;
typedef __attribute__((ext_vector_type(4))) _Float16 f16x4;
typedef __attribute__((ext_vector_type(4))) float f32x4;

#define GLOAD16(gp, lp)                                                        \
  __builtin_amdgcn_global_load_lds(                                            \
      (const __attribute__((address_space(1))) unsigned int*)(const void*)(gp),\
      (__attribute__((address_space(3))) unsigned int*)(void*)(lp), 16, 0, 0)

__device__ __forceinline__ unsigned short f32_to_bf16(float f) {
  unsigned u = __float_as_uint(f);
  unsigned r = (u + 0x7fffu + ((u >> 16) & 1u)) >> 16;
  return (unsigned short)r;
}
__device__ __forceinline__ float bf16_to_f32(unsigned short h) {
  return __uint_as_float(((unsigned)h) << 16);
}

// ---------------- proj: threefry2x32 (partitionable) + erfinv ----------------
__device__ __forceinline__ unsigned rotl32(unsigned x, int r) {
  return (x << r) | (x >> (32 - r));
}

__device__ __forceinline__ float erfinv_f32(float x) {
  float w = -log1pf(-x * x);
  float p;
  if (w < 5.0f) {
    w -= 2.5f;
    p = 2.81022636e-08f;
    p = fmaf(p, w, 3.43273939e-07f);
    p = fmaf(p, w, -3.5233877e-06f);
    p = fmaf(p, w, -4.39150654e-06f);
    p = fmaf(p, w, 0.00021858087f);
    p = fmaf(p, w, -0.00125372503f);
    p = fmaf(p, w, -0.00417768164f);
    p = fmaf(p, w, 0.246640727f);
    p = fmaf(p, w, 1.50140941f);
  } else {
    w = sqrtf(w) - 3.0f;
    p = -0.000200214257f;
    p = fmaf(p, w, 0.000100950558f);
    p = fmaf(p, w, 0.00134934322f);
    p = fmaf(p, w, -0.00367342844f);
    p = fmaf(p, w, 0.00573950773f);
    p = fmaf(p, w, -0.0076224613f);
    p = fmaf(p, w, 0.00943887047f);
    p = fmaf(p, w, 1.00167406f);
    p = fmaf(p, w, 2.83297682f);
  }
  return p * x;
}

__device__ __forceinline__ float bits_to_normal(unsigned b) {
  float f = __uint_as_float((b >> 9) | 0x3f800000u) - 1.0f;
  const float lo = -0.9999999403953552f;
  float u = fmaxf(lo, fmaf(f, 2.0f, lo));
  return 1.4142135623730951f * erfinv_f32(u);
}

__global__ void proj_kernel(float* __restrict__ proj) {
  int i = blockIdx.x * blockDim.x + threadIdx.x;
  if (i >= 4096) return;
  unsigned k0 = 0u, k1 = 42u;
  unsigned k2 = 0x1BD11BDAu ^ k0 ^ k1;
  unsigned x0 = 0u, x1 = (unsigned)i;
  x0 += k0; x1 += k1;
#define QR(r) { x0 += x1; x1 = rotl32(x1, r); x1 ^= x0; }
  QR(13) QR(15) QR(26) QR(6)   x0 += k1; x1 += k2 + 1u;
  QR(17) QR(29) QR(16) QR(24)  x0 += k2; x1 += k0 + 2u;
  QR(13) QR(15) QR(26) QR(6)   x0 += k0; x1 += k1 + 3u;
  QR(17) QR(29) QR(16) QR(24)  x0 += k1; x1 += k2 + 4u;
  QR(13) QR(15) QR(26) QR(6)   x0 += k2; x1 += k0 + 5u;
#undef QR
  proj[i] = bits_to_normal(x0 ^ x1) / 5.656854249492381f;
}

// ---------------- RoPE tables ----------------
__global__ void rope_table_kernel(float* __restrict__ cosb, float* __restrict__ sinb) {
  int s = blockIdx.x;
  int j = threadIdx.x;
  double e = (double)(2 * j) / 128.0;
  double invf = 1.0 / pow(10000.0, e);
  float freq = (float)s * (float)invf;
  cosb[s * 64 + j] = (float)cos((double)freq);
  sinb[s * 64 + j] = (float)sin((double)freq);
}

// ---------------- x -> bf16 hi/lo + fp16, single pass ----------------
__global__ __launch_bounds__(256) void split_x3_kernel(const float* __restrict__ in,
                                                       unsigned short* __restrict__ hi,
                                                       unsigned short* __restrict__ lo,
                                                       _Float16* __restrict__ f16,
                                                       int n4) {
  int i = blockIdx.x * blockDim.x + threadIdx.x;
  if (i >= n4) return;
  float4 v = ((const float4*)in)[i];
  ushort4 hv, lv;
  f16x4 fv;
  hv.x = f32_to_bf16(v.x); lv.x = f32_to_bf16(v.x - bf16_to_f32(hv.x)); fv[0] = (_Float16)v.x;
  hv.y = f32_to_bf16(v.y); lv.y = f32_to_bf16(v.y - bf16_to_f32(hv.y)); fv[1] = (_Float16)v.y;
  hv.z = f32_to_bf16(v.z); lv.z = f32_to_bf16(v.z - bf16_to_f32(hv.z)); fv[2] = (_Float16)v.z;
  hv.w = f32_to_bf16(v.w); lv.w = f32_to_bf16(v.w - bf16_to_f32(hv.w)); fv[3] = (_Float16)v.w;
  ((ushort4*)hi)[i] = hv;
  ((ushort4*)lo)[i] = lv;
  ((f16x4*)f16)[i] = fv;
}

// ---------------- W -> bf16 hi/lo (for Wk) ----------------
__global__ __launch_bounds__(256) void split_kernel(const float* __restrict__ in,
                                                    unsigned short* __restrict__ hi,
                                                    unsigned short* __restrict__ lo,
                                                    int n4) {
  int i = blockIdx.x * blockDim.x + threadIdx.x;
  if (i >= n4) return;
  float4 v = ((const float4*)in)[i];
  ushort4 hv, lv;
  hv.x = f32_to_bf16(v.x); lv.x = f32_to_bf16(v.x - bf16_to_f32(hv.x));
  hv.y = f32_to_bf16(v.y); lv.y = f32_to_bf16(v.y - bf16_to_f32(hv.y));
  hv.z = f32_to_bf16(v.z); lv.z = f32_to_bf16(v.z - bf16_to_f32(hv.z));
  hv.w = f32_to_bf16(v.w); lv.w = f32_to_bf16(v.w - bf16_to_f32(hv.w));
  ((ushort4*)hi)[i] = hv;
  ((ushort4*)lo)[i] = lv;
}

// ---------------- W -> fp16 ----------------
__global__ __launch_bounds__(256) void split_f16_kernel(const float* __restrict__ in,
                                                        _Float16* __restrict__ f16,
                                                        int n4) {
  int i = blockIdx.x * blockDim.x + threadIdx.x;
  if (i >= n4) return;
  float4 v = ((const float4*)in)[i];
  f16x4 fv;
  fv[0] = (_Float16)v.x; fv[1] = (_Float16)v.y;
  fv[2] = (_Float16)v.z; fv[3] = (_Float16)v.w;
  ((f16x4*)f16)[i] = fv;
}

// ---------------- k-GEMM: bf16x3, 256x256, 8 waves, SPLIT-K=2, 4-phase ------
__global__ __launch_bounds__(512, 2) void mfma_gemm_k_sk(const unsigned short* __restrict__ Ahi,
                                                         const unsigned short* __restrict__ Alo,
                                                         const unsigned short* __restrict__ Whi,
                                                         const unsigned short* __restrict__ Wlo,
                                                         float* __restrict__ kp0,
                                                         float* __restrict__ kp1) {
  __shared__ char smem[131072];  // 2 buf x 64K: Ahi 0|Alo 16K|Bhi 32K|Blo 48K
  const int t = threadIdx.x, l = t & 63, w = t >> 6;  // 8 waves
  const int lin = blockIdx.z * 128 + blockIdx.y * 8 + blockIdx.x;
  const int swz = (lin & 7) * 32 + (lin >> 3);        // 256 blocks, bijective
  const int kz = swz >> 7;
  const int idx = swz & 127;
  const int n0 = (idx & 7) * 256;
  const int m0 = (idx >> 3) * 256;
  const int kbase = kz * 1024;
  float* C = kz ? kp1 : kp0;
  const int wm = w >> 2, wn = w & 3;                  // 2M x 4N wave grid
  const int lr = l & 15;
  const int lg8 = (l >> 4) * 8;
  const size_t rstep = (size_t)16 * DM;

  const unsigned short* gAh = Ahi + (size_t)(m0 + w * 32 + lr) * DM + lg8;
  const unsigned short* gAl = Alo + (size_t)(m0 + w * 32 + lr) * DM + lg8;
  const unsigned short* gBh = Whi + (size_t)(n0 + w * 32 + lr) * DM + lg8;
  const unsigned short* gBl = Wlo + (size_t)(n0 + w * 32 + lr) * DM + lg8;

  f32x4 acc[8][4];
#pragma unroll
  for (int i = 0; i < 8; ++i)
#pragma unroll
    for (int j = 0; j < 4; ++j) acc[i][j] = (f32x4){0.f, 0.f, 0.f, 0.f};

  {  // prologue: full stage of tile 0 into buf 0
    char* base = smem + w * 2048;
    GLOAD16(gAh + kbase, base);
    GLOAD16(gAh + rstep + kbase, base + 1024);
    GLOAD16(gAl + kbase, base + 16384);
    GLOAD16(gAl + rstep + kbase, base + 16384 + 1024);
    GLOAD16(gBh + kbase, base + 32768);
    GLOAD16(gBh + rstep + kbase, base + 32768 + 1024);
    GLOAD16(gBl + kbase, base + 49152);
    GLOAD16(gBl + rstep + kbase, base + 49152 + 1024);
  }
  int cur = 0;

#define KQUAD(q)                                                                        \
  {                                                                                     \
    short8 ah0 = *(const short8*)(buf + (wm * 8 + 2 * (q)) * 1024 + l * 16);            \
    short8 ah1 = *(const short8*)(buf + (wm * 8 + 2 * (q) + 1) * 1024 + l * 16);        \
    short8 al0 = *(const short8*)(buf + 16384 + (wm * 8 + 2 * (q)) * 1024 + l * 16);    \
    short8 al1 = *(const short8*)(buf + 16384 + (wm * 8 + 2 * (q) + 1) * 1024 + l * 16);\
    __builtin_amdgcn_s_setprio(1);                                                      \
    _Pragma("unroll")                                                                   \
    for (int n = 0; n < 4; ++n) {                                                       \
      acc[2 * (q)][n] = __builtin_amdgcn_mfma_f32_16x16x32_bf16(ah0, bh[n], acc[2 * (q)][n], 0, 0, 0); \
      acc[2 * (q)][n] = __builtin_amdgcn_mfma_f32_16x16x32_bf16(ah0, bl[n], acc[2 * (q)][n], 0, 0, 0); \
      acc[2 * (q)][n] = __builtin_amdgcn_mfma_f32_16x16x32_bf16(al0, bh[n], acc[2 * (q)][n], 0, 0, 0); \
    }                                                                                   \
    _Pragma("unroll")                                                                   \
    for (int n = 0; n < 4; ++n) {                                                       \
      acc[2 * (q) + 1][n] = __builtin_amdgcn_mfma_f32_16x16x32_bf16(ah1, bh[n], acc[2 * (q) + 1][n], 0, 0, 0); \
      acc[2 * (q) + 1][n] = __builtin_amdgcn_mfma_f32_16x16x32_bf16(ah1, bl[n], acc[2 * (q) + 1][n], 0, 0, 0); \
      acc[2 * (q) + 1][n] = __builtin_amdgcn_mfma_f32_16x16x32_bf16(al1, bh[n], acc[2 * (q) + 1][n], 0, 0, 0); \
    }                                                                                   \
    __builtin_amdgcn_s_setprio(0);                                                      \
  }

  for (int k0 = kbase; k0 < kbase + 1024; k0 += 32) {
    const bool more = (k0 + 32 < kbase + 1024);
    char* buf = smem + cur * 65536;
    char* nb = smem + (cur ^ 1) * 65536 + w * 2048;
    const int kn = k0 + 32;

    if (more) {
      GLOAD16(gBh + kn, nb + 32768);
      GLOAD16(gBh + rstep + kn, nb + 32768 + 1024);
      asm volatile("s_waitcnt vmcnt(2)" ::: "memory");
    } else {
      asm volatile("s_waitcnt vmcnt(0)" ::: "memory");
    }
    __builtin_amdgcn_s_barrier();

    short8 bh[4], bl[4];
#pragma unroll
    for (int f = 0; f < 4; ++f) {
      bh[f] = *(const short8*)(buf + 32768 + (wn * 4 + f) * 1024 + l * 16);
      bl[f] = *(const short8*)(buf + 49152 + (wn * 4 + f) * 1024 + l * 16);
    }
    KQUAD(0);
    __builtin_amdgcn_s_barrier();

    if (more) {
      GLOAD16(gBl + kn, nb + 49152);
      GLOAD16(gBl + rstep + kn, nb + 49152 + 1024);
    }
    KQUAD(1);
    __builtin_amdgcn_s_barrier();

    if (more) {
      GLOAD16(gAh + kn, nb);
      GLOAD16(gAh + rstep + kn, nb + 1024);
    }
    KQUAD(2);
    __builtin_amdgcn_s_barrier();

    if (more) {
      GLOAD16(gAl + kn, nb + 16384);
      GLOAD16(gAl + rstep + kn, nb + 16384 + 1024);
    }
    KQUAD(3);
    __builtin_amdgcn_s_barrier();

    cur ^= 1;
  }
#undef KQUAD

#pragma unroll
  for (int m = 0; m < 8; ++m) {
    int row0 = m0 + wm * 128 + m * 16 + (l >> 4) * 4;
#pragma unroll
    for (int n = 0; n < 4; ++n) {
      int col = n0 + wn * 64 + n * 16 + (l & 15);
      int h = col >> 7, d = col & 127;
#pragma unroll
      for (int r = 0; r < 4; ++r) {
        int mm = row0 + r;
        int b = mm >> 11, s = mm & (S_ - 1);
        C[(((size_t)(b * H_ + h) * S_) + s) * DH + d] = acc[m][n][r];
      }
    }
  }
}

// ---------------- fused q+V fp16 GEMM: 256x256, 8 waves, 2-phase ------------
__global__ __launch_bounds__(512, 2) void mfma_gemm_qv(const _Float16* __restrict__ A,
                                                       const _Float16* __restrict__ W,
                                                       float* __restrict__ Cq,
                                                       _Float16* __restrict__ vt) {
  __shared__ char smem[65536];  // 2 buf x 32K: A frags 0..16K | B frags 16..32K
  const int t = threadIdx.x, l = t & 63, w = t >> 6;  // 8 waves
  const int lin = blockIdx.y * gridDim.x + blockIdx.x;
  const int swz = (lin & 7) * 32 + (lin >> 3);        // 256 blocks, bijective
  const int n0 = (swz & 15) * 256;
  const int m0 = (swz >> 4) * 256;
  const int wm = w >> 2, wn = w & 3;                  // 2M x 4N wave grid
  const int lr = l & 15;
  const int lg8 = (l >> 4) * 8;
  const size_t rstep = (size_t)16 * DM;

  const _Float16* gA = A + (size_t)(m0 + w * 32 + lr) * DM + lg8;
  const _Float16* gB = W + (size_t)(n0 + w * 32 + lr) * DM + lg8;

  f32x4 acc[8][4];
#pragma unroll
  for (int i = 0; i < 8; ++i)
#pragma unroll
    for (int j = 0; j < 4; ++j) acc[i][j] = (f32x4){0.f, 0.f, 0.f, 0.f};

  {  // prologue
    char* base = smem + w * 2048;
    GLOAD16(gA, base);
    GLOAD16(gA + rstep, base + 1024);
    GLOAD16(gB, base + 16384);
    GLOAD16(gB + rstep, base + 16384 + 1024);
  }
  int cur = 0;

  for (int k0 = 0; k0 < DM; k0 += 32) {
    const bool more = (k0 + 32 < DM);
    char* buf = smem + cur * 32768;
    char* nb = smem + (cur ^ 1) * 32768 + w * 2048;
    const int kn = k0 + 32;

    if (more) {
      GLOAD16(gA + kn, nb);
      GLOAD16(gA + rstep + kn, nb + 1024);
      asm volatile("s_waitcnt vmcnt(2)" ::: "memory");
    } else {
      asm volatile("s_waitcnt vmcnt(0)" ::: "memory");
    }
    __builtin_amdgcn_s_barrier();

    f16x8 b[4];
#pragma unroll
    for (int j = 0; j < 4; ++j)
      b[j] = *(const f16x8*)(buf + 16384 + (wn * 4 + j) * 1024 + l * 16);
    __builtin_amdgcn_s_setprio(1);
#pragma unroll
    for (int i = 0; i < 4; ++i) {
      f16x8 a = *(const f16x8*)(buf + (wm * 8 + i) * 1024 + l * 16);
#pragma unroll
      for (int j = 0; j < 4; ++j)
        acc[i][j] = __builtin_amdgcn_mfma_f32_16x16x32_f16(a, b[j], acc[i][j], 0, 0, 0);
    }
    __builtin_amdgcn_s_setprio(0);
    __builtin_amdgcn_s_barrier();

    if (more) {
      GLOAD16(gB + kn, nb + 16384);
      GLOAD16(gB + rstep + kn, nb + 16384 + 1024);
    }
    __builtin_amdgcn_s_setprio(1);
#pragma unroll
    for (int i = 4; i < 8; ++i) {
      f16x8 a = *(const f16x8*)(buf + (wm * 8 + i) * 1024 + l * 16);
#pragma unroll
      for (int j = 0; j < 4; ++j)
        acc[i][j] = __builtin_amdgcn_mfma_f32_16x16x32_f16(a, b[j], acc[i][j], 0, 0, 0);
    }
    __builtin_amdgcn_s_setprio(0);
    __builtin_amdgcn_s_barrier();

    cur ^= 1;
  }

#pragma unroll
  for (int m = 0; m < 8; ++m) {
    int row0 = m0 + wm * 128 + m * 16 + (l >> 4) * 4;
#pragma unroll
    for (int n = 0; n < 4; ++n) {
      int col = n0 + wn * 64 + n * 16 + (l & 15);
      if (col < DM) {
        int h = col >> 7, d = col & 127;
#pragma unroll
        for (int r = 0; r < 4; ++r) {
          int mm = row0 + r;
          int b2 = mm >> 11, s = mm & (S_ - 1);
          Cq[(((size_t)(b2 * H_ + h) * S_) + s) * DH + d] = acc[m][n][r];
        }
      } else {
        int vcol = col - DM;
        int h = vcol >> 7, d = vcol & 127;
        int b2 = row0 >> 11, s0 = row0 & (S_ - 1);
        f16x4 vv;
        vv[0] = (_Float16)acc[m][n][0];
        vv[1] = (_Float16)acc[m][n][1];
        vv[2] = (_Float16)acc[m][n][2];
        vv[3] = (_Float16)acc[m][n][3];
        *(f16x4*)(vt + (((size_t)(b2 * H_ + h)) * DH + d) * S_ + s0) = vv;
      }
    }
  }
}

// ---------------- fp16 single-product GEMM (O), BK=64, 128x128 --------------
template <int MODE>
__global__ __launch_bounds__(256) void mfma_gemm_f16(const _Float16* __restrict__ A,
                                                     const _Float16* __restrict__ W,
                                                     void* __restrict__ Cout) {
  __shared__ char smem[65536];
  const int t = threadIdx.x, l = t & 63, w = t >> 6;
  const int lin = blockIdx.y * gridDim.x + blockIdx.x;
  const int cpx = (gridDim.x * gridDim.y) >> 3;
  const int swz = (lin & 7) * cpx + (lin >> 3);
  const int n0 = (swz % gridDim.x) * 128;
  const int m0 = (swz / gridDim.x) * 128;
  const int wm = w >> 1, wn = w & 1;
  const int lr = l & 15;
  const int lg8 = (l >> 4) * 8;

  auto STAGE = [&](int k0, int c) {
    char* base = smem + c * 32768;
#pragma unroll
    for (int f0 = 0; f0 < 4; ++f0) {
      int f = w * 4 + f0;
      int rb = f >> 1, kh = f & 1;
      GLOAD16(A + (size_t)(m0 + rb * 16 + lr) * DM + k0 + kh * 32 + lg8,
              base + f * 1024);
      GLOAD16(W + (size_t)(n0 + rb * 16 + lr) * DM + k0 + kh * 32 + lg8,
              base + 16384 + f * 1024);
    }
  };

  f32x4 acc[4][4];
#pragma unroll
  for (int i = 0; i < 4; ++i)
#pragma unroll
    for (int j = 0; j < 4; ++j) acc[i][j] = (f32x4){0.f, 0.f, 0.f, 0.f};

  STAGE(0, 0);
  int cur = 0;

  for (int k0 = 0; k0 < DM; k0 += 64) {
    if (k0 + 64 < DM) {
      STAGE(k0 + 64, cur ^ 1);
      asm volatile("s_waitcnt vmcnt(8)" ::: "memory");
    } else {
      asm volatile("s_waitcnt vmcnt(0)" ::: "memory");
    }
    __builtin_amdgcn_s_barrier();

    char* buf = smem + cur * 32768;
    f16x8 a[4][2], b[4][2];
#pragma unroll
    for (int i = 0; i < 4; ++i)
#pragma unroll
      for (int kh = 0; kh < 2; ++kh) {
        a[i][kh] = *(const f16x8*)(buf + ((wm * 4 + i) * 2 + kh) * 1024 + l * 16);
        b[i][kh] = *(const f16x8*)(buf + 16384 + ((wn * 4 + i) * 2 + kh) * 1024 + l * 16);
      }
    __builtin_amdgcn_s_setprio(1);
#pragma unroll
    for (int i = 0; i < 4; ++i)
#pragma unroll
      for (int j = 0; j < 4; ++j) {
        acc[i][j] = __builtin_amdgcn_mfma_f32_16x16x32_f16(a[i][0], b[j][0], acc[i][j], 0, 0, 0);
        acc[i][j] = __builtin_amdgcn_mfma_f32_16x16x32_f16(a[i][1], b[j][1], acc[i][j], 0, 0, 0);
      }
    __builtin_amdgcn_s_setprio(0);
    __builtin_amdgcn_s_barrier();
    cur ^= 1;
  }

#pragma unroll
  for (int i = 0; i < 4; ++i) {
    int row0 = m0 + wm * 64 + i * 16 + (l >> 4) * 4;
#pragma unroll
    for (int j = 0; j < 4; ++j) {
      int col = n0 + wn * 64 + j * 16 + (l & 15);
      if constexpr (MODE == 1) {
        float* C = (float*)Cout;
#pragma unroll
        for (int r = 0; r < 4; ++r)
          C[(size_t)(row0 + r) * DM + col] = acc[i][j][r];
      }
    }
  }
}

// ---------------- RMSNorm + RoPE for K: sums split-K partials, emits fp16 ---
__global__ __launch_bounds__(256) void rmsrope_k_kernel(float* __restrict__ k,
                                                        const float* __restrict__ kp1,
                                                        _Float16* __restrict__ kf,
                                                        const float* __restrict__ cosb,
                                                        const float* __restrict__ sinb) {
  int w = threadIdx.x >> 6;
  int lane = threadIdx.x & 63;
  long r = (long)blockIdx.x * 4 + w;
  float* p = k + r * DH;
  const float* p1 = kp1 + r * DH;
  int s = (int)(r & (S_ - 1));
  float x1 = p[lane] + p1[lane];
  float x2 = p[lane + 64] + p1[lane + 64];
  float ss = fmaf(x1, x1, x2 * x2);
#pragma unroll
  for (int off = 32; off; off >>= 1) ss += __shfl_xor(ss, off);
  float rms = rsqrtf(ss * (1.0f / 128.0f) + 1e-6f);
  float n1 = x1 * rms, n2 = x2 * rms;
  float c = cosb[s * 64 + lane], sn = sinb[s * 64 + lane];
  float o1 = fmaf(n1, c, n2 * sn);
  float o2 = fmaf(-n1, sn, n2 * c);
  p[lane] = o1;
  p[lane + 64] = o2;
  kf[r * DH + lane] = (_Float16)o1;
  kf[r * DH + lane + 64] = (_Float16)o2;
}

// ---------------- RMSNorm + RoPE + gain for Q, in place ----------------
__global__ __launch_bounds__(256) void rmsrope_q_kernel(float* __restrict__ q,
                                                        const float* __restrict__ cosb,
                                                        const float* __restrict__ sinb,
                                                        const float* __restrict__ qg) {
  int w = threadIdx.x >> 6;
  int lane = threadIdx.x & 63;
  long r = (long)blockIdx.x * 4 + w;
  float* p = q + r * DH;
  int s = (int)(r & (S_ - 1));
  int h = (int)((r >> 11) & (H_ - 1));
  float x1 = p[lane], x2 = p[lane + 64];
  float ss = fmaf(x1, x1, x2 * x2);
#pragma unroll
  for (int off = 32; off; off >>= 1) ss += __shfl_xor(ss, off);
  float rms = rsqrtf(ss * (1.0f / 128.0f) + 1e-6f);
  float n1 = x1 * rms, n2 = x2 * rms;
  float c = cosb[s * 64 + lane], sn = sinb[s * 64 + lane];
  float g = qg[h];
  float o1 = fmaf(n1, c, n2 * sn) * g;
  float o2 = fmaf(-n1, sn, n2 * c) * g;
  p[lane] = o1;
  p[lane + 64] = o2;
}

// ---------------- selection phase 1: q-mean partial sums ----------------
__global__ __launch_bounds__(256) void qmean_part_kernel(const float* __restrict__ q,
                                                         float* __restrict__ partial) {
  __shared__ float red[256];
  const int bh = blockIdx.x >> 4, chunk = blockIdx.x & 15;
  const int t = threadIdx.x;
  const int d = t & 127, half = t >> 7;
  const float* qb = q + ((size_t)bh * S_ + chunk * 128 + half * 64) * DH;
  float sum = 0.0f;
#pragma unroll 4
  for (int s = 0; s < 64; ++s) sum += qb[(size_t)s * DH + d];
  red[t] = sum;
  __syncthreads();
  if (t < 128) partial[(size_t)blockIdx.x * 128 + t] = red[t] + red[t + 128];
}

// ---------------- selection phase 2: finish mean, project, normalize --------
__global__ void qproj_kernel(const float* __restrict__ partial,
                             const float* __restrict__ proj,
                             float* __restrict__ qp) {
  __shared__ float meanq[128];
  __shared__ float qps[32];
  __shared__ float nrm;
  const int bh = blockIdx.x, t = threadIdx.x;
  float s = 0.0f;
#pragma unroll
  for (int c = 0; c < 16; ++c) s += partial[((size_t)bh * 16 + c) * 128 + t];
  meanq[t] = s * (1.0f / 2048.0f);
  __syncthreads();
  if (t < 32) {
    float sum = 0.0f;
    for (int d = 0; d < 128; ++d) sum = fmaf(meanq[d], proj[d * 32 + t], sum);
    qps[t] = sum;
  }
  __syncthreads();
  if (t == 0) {
    float sum = 0.0f;
    for (int j = 0; j < 32; ++j) sum += qps[j] * qps[j];
    nrm = 1.0f / fmaxf(sqrtf(sum), 1e-12f);
  }
  __syncthreads();
  if (t < 32) qp[bh * 32 + t] = qps[t] * nrm;
}

// ---------------- selection phase 3: per-(bh,block) score ----------------
__global__ __launch_bounds__(256) void kscore_kernel(const float* __restrict__ k,
                                                     const float* __restrict__ proj,
                                                     const float* __restrict__ qp,
                                                     float* __restrict__ scores) {
  __shared__ float ps[128][32];
  __shared__ float kp[64][33];
  __shared__ float cent[33];
  __shared__ float nrm;
  const int bh = blockIdx.x >> 5, n = blockIdx.x & 31;
  const int t = threadIdx.x;
  for (int i = t; i < 4096; i += 256) ps[i >> 5][i & 31] = proj[i];
  const float* kn = k + ((size_t)bh * S_ + n * 64) * DH;
  __syncthreads();
  {
    int row = t >> 2, j0 = (t & 3) * 8;
    float accv[8];
#pragma unroll
    for (int jj = 0; jj < 8; ++jj) accv[jj] = 0.0f;
#pragma unroll 4
    for (int d = 0; d < 128; ++d) {
      float kv = kn[(size_t)row * DH + d];
#pragma unroll
      for (int jj = 0; jj < 8; ++jj) accv[jj] = fmaf(kv, ps[d][j0 + jj], accv[jj]);
    }
#pragma unroll
    for (int jj = 0; jj < 8; ++jj) kp[row][j0 + jj] = accv[jj];
  }
  __syncthreads();
  if (t < 64) {
    float sum = 0.0f;
    for (int j = 0; j < 32; ++j) sum += kp[t][j] * kp[t][j];
    float scl = 1.0f / fmaxf(sqrtf(sum), 1e-12f);
    for (int j = 0; j < 32; ++j) kp[t][j] *= scl;
  }
  __syncthreads();
  if (t < 32) {
    float sum = 0.0f;
    for (int r2 = 0; r2 < 64; ++r2) sum += kp[r2][t];
    cent[t] = sum * (1.0f / 64.0f);
  }
  __syncthreads();
  if (t == 0) {
    float sum = 0.0f;
    for (int j = 0; j < 32; ++j) sum += cent[j] * cent[j];
    nrm = 1.0f / fmaxf(sqrtf(sum), 1e-12f);
  }
  __syncthreads();
  if (t < 32) cent[t] *= nrm;
  __syncthreads();
  if (t < 64) {
    float dt = 0.0f;
    for (int j = 0; j < 32; ++j) dt = fmaf(kp[t][j], cent[j], dt);
#pragma unroll
    for (int off = 32; off; off >>= 1) dt = fminf(dt, __shfl_xor(dt, off));
    if (t == 0) {
      float radius = fminf(fmaxf(1.0f - dt, 0.0f), 1.0f);
      float dq = 0.0f;
      for (int j = 0; j < 32; ++j) dq = fmaf(qp[bh * 32 + j], cent[j], dq);
      scores[bh * 32 + n] = dq + radius;
    }
  }
}

// ---------------- selection phase 4: top-18 + sort ----------------
__global__ void topk_kernel(const float* __restrict__ scores, int* __restrict__ top_idx) {
  if (threadIdx.x != 0) return;
  const int bh = blockIdx.x;
  float sc[NBLK];
  for (int j = 0; j < NBLK; ++j) sc[j] = scores[bh * 32 + j];
  sc[NBLK - 2] = INFINITY;
  sc[NBLK - 1] = INFINITY;
  int chosen[NKEEP];
  bool used[NBLK];
  for (int j = 0; j < NBLK; ++j) used[j] = false;
  for (int kk = 0; kk < NKEEP; ++kk) {
    int best = -1;
    float bv = 0.0f;
    for (int j = 0; j < NBLK; ++j)
      if (!used[j] && (best < 0 || sc[j] > bv)) { bv = sc[j]; best = j; }
    used[best] = true;
    chosen[kk] = best;
  }
  for (int a = 1; a < NKEEP; ++a) {
    int v2 = chosen[a], b2 = a - 1;
    while (b2 >= 0 && chosen[b2] > v2) { chosen[b2 + 1] = chosen[b2]; --b2; }
    chosen[b2 + 1] = v2;
  }
  for (int a = 0; a < NKEEP; ++a) top_idx[bh * NKEEP + a] = chosen[a];
}

// ---------------- MFMA attention v5: 8 waves / 128 q-rows, defer-max --------
// grid = BH*16; 512 threads. K/V staging shared by 8 waves (4 gloads/wave);
// counted-vmcnt double buffer; T13 defer-max (THR=8) skips rescale.
__global__ __launch_bounds__(512, 1) void attn_mfma_kernel(const float* __restrict__ q,
                                                           const _Float16* __restrict__ kf,
                                                           const _Float16* __restrict__ vt,
                                                           const int* __restrict__ top_idx,
                                                           _Float16* __restrict__ yf) {
  __shared__ char lds[83968];  // buf0 0..32K (K 16K|V 16K), buf1 32..64K, P 64K.. (8x2304)
  const int bh = blockIdx.x >> 4;
  const int qt = blockIdx.x & 15;
  const int t = threadIdx.x, l = t & 63, w = t >> 6;  // 8 waves
  const int lr = l & 15, lg = l >> 4;
  const float scale = 0.08838834764831843f;  // 1/sqrt(128)

  f16x8 qf[4];
  {
    const float* qbase = q + ((size_t)(bh * S_ + qt * 128 + w * 16 + lr)) * DH + lg * 8;
#pragma unroll
    for (int dc = 0; dc < 4; ++dc) {
      float4 v0 = *(const float4*)(qbase + dc * 32);
      float4 v1 = *(const float4*)(qbase + dc * 32 + 4);
      f16x8 h;
      h[0] = (_Float16)v0.x; h[1] = (_Float16)v0.y; h[2] = (_Float16)v0.z; h[3] = (_Float16)v0.w;
      h[4] = (_Float16)v1.x; h[5] = (_Float16)v1.y; h[6] = (_Float16)v1.z; h[7] = (_Float16)v1.w;
      qf[dc] = h;
    }
  }

  float m_[4] = {-INFINITY, -INFINITY, -INFINITY, -INFINITY};
  float ls[4] = {0.f, 0.f, 0.f, 0.f};
  f32x4 yacc[8];
#pragma unroll
  for (int dt = 0; dt < 8; ++dt) yacc[dt] = (f32x4){0.f, 0.f, 0.f, 0.f};

  char* Pw = lds + 65536 + w * 2304;  // per-wave P: [16 q][72 fp16]

  const _Float16* kb0 = kf + (size_t)bh * S_ * DH;
  const _Float16* vb0 = vt + (size_t)bh * DH * S_;
  const int* idxp = top_idx + bh * NKEEP;

  // 8 waves share staging: wave stages K frags {2w,2w+1} + V frags {2w,2w+1}
  auto STAGE = [&](int blk, int c) {
    char* base = lds + c * 32768;
#pragma unroll
    for (int f0 = 0; f0 < 2; ++f0) {
      int f = w * 2 + f0;
      int kt = f >> 2, dc = f & 3;
      GLOAD16(kb0 + (size_t)(blk * 64 + kt * 16 + lr) * DH + dc * 32 + lg * 8,
              base + f * 1024);
      int K0 = f >> 3, dt = f & 7;
      GLOAD16(vb0 + (size_t)(dt * 16 + lr) * S_ + blk * 64 + K0 * 32 + lg * 8,
              base + 16384 + f * 1024);
    }
  };

  int cur = 0;
  STAGE(idxp[0], 0);

  for (int it = 0; it < NKEEP; ++it) {
    if (it + 1 < NKEEP) {
      STAGE(idxp[it + 1], cur ^ 1);
      asm volatile("s_waitcnt vmcnt(4)" ::: "memory");
    } else {
      asm volatile("s_waitcnt vmcnt(0)" ::: "memory");
    }
    __builtin_amdgcn_s_barrier();
    char* buf = lds + cur * 32768;

    f32x4 sacc[4];
#pragma unroll
    for (int kt = 0; kt < 4; ++kt) sacc[kt] = (f32x4){0.f, 0.f, 0.f, 0.f};
    __builtin_amdgcn_s_setprio(1);
#pragma unroll
    for (int kt = 0; kt < 4; ++kt)
#pragma unroll
      for (int dc = 0; dc < 4; ++dc) {
        f16x8 kfr = *(const f16x8*)(buf + (kt * 4 + dc) * 1024 + l * 16);
        sacc[kt] = __builtin_amdgcn_mfma_f32_16x16x32_f16(qf[dc], kfr, sacc[kt], 0, 0, 0);
      }
    __builtin_amdgcn_s_setprio(0);

    // per-row tile max (reduced over the row's 16 lanes)
    float mt[4];
#pragma unroll
    for (int r = 0; r < 4; ++r) {
      float mv = fmaxf(fmaxf(sacc[0][r], sacc[1][r]), fmaxf(sacc[2][r], sacc[3][r])) * scale;
#pragma unroll
      for (int off = 1; off < 16; off <<= 1) mv = fmaxf(mv, __shfl_xor(mv, off));
      mt[r] = mv;
    }
    float p[4][4];
    bool ok = (mt[0] <= m_[0] + 8.0f) && (mt[1] <= m_[1] + 8.0f) &&
              (mt[2] <= m_[2] + 8.0f) && (mt[3] <= m_[3] + 8.0f);
    if (__all(ok)) {
      // defer-max: keep old max, no rescale (P bounded by e^8)
#pragma unroll
      for (int r = 0; r < 4; ++r) {
        float rs = 0.f;
#pragma unroll
        for (int kt = 0; kt < 4; ++kt) {
          p[kt][r] = __expf(fmaf(sacc[kt][r], scale, -m_[r]));
          rs += p[kt][r];
        }
#pragma unroll
        for (int off = 1; off < 16; off <<= 1) rs += __shfl_xor(rs, off);
        ls[r] += rs;
      }
    } else {
#pragma unroll
      for (int r = 0; r < 4; ++r) {
        float mn = fmaxf(m_[r], mt[r]);
        float corr = __expf(m_[r] - mn);
        float rs = 0.f;
#pragma unroll
        for (int kt = 0; kt < 4; ++kt) {
          p[kt][r] = __expf(fmaf(sacc[kt][r], scale, -mn));
          rs += p[kt][r];
        }
#pragma unroll
        for (int off = 1; off < 16; off <<= 1) rs += __shfl_xor(rs, off);
        ls[r] = ls[r] * corr + rs;
        m_[r] = mn;
#pragma unroll
        for (int dt = 0; dt < 8; ++dt) yacc[dt][r] *= corr;
      }
    }

#pragma unroll
    for (int kt = 0; kt < 4; ++kt)
#pragma unroll
      for (int r = 0; r < 4; ++r)
        *(_Float16*)(Pw + (lg * 4 + r) * 144 + (kt * 16 + lr) * 2) = (_Float16)p[kt][r];

    __builtin_amdgcn_s_setprio(1);
#pragma unroll
    for (int K0 = 0; K0 < 2; ++K0) {
      f16x8 pa = *(const f16x8*)(Pw + lr * 144 + K0 * 64 + lg * 16);
#pragma unroll
      for (int dt = 0; dt < 8; ++dt) {
        f16x8 vf = *(const f16x8*)(buf + 16384 + (K0 * 8 + dt) * 1024 + l * 16);
        yacc[dt] = __builtin_amdgcn_mfma_f32_16x16x32_f16(pa, vf, yacc[dt], 0, 0, 0);
      }
    }
    __builtin_amdgcn_s_setprio(0);

    __builtin_amdgcn_s_barrier();
    cur ^= 1;
  }

  const int b = bh >> 4, h = bh & (H_ - 1);
  float inv[4];
#pragma unroll
  for (int r = 0; r < 4; ++r) inv[r] = 1.0f / ls[r];
#pragma unroll
  for (int r = 0; r < 4; ++r) {
    int srow = qt * 128 + w * 16 + lg * 4 + r;
    size_t off0 = ((size_t)b * S_ + srow) * DM + h * DH + lr;
#pragma unroll
    for (int dt = 0; dt < 8; ++dt)
      yf[off0 + dt * 16] = (_Float16)(yacc[dt][r] * inv[r]);
  }
}

extern "C" void kernel_launch(void* const* d_in, const int* in_sizes, int n_in,
                              void* d_out, int out_size, void* d_ws, size_t ws_size,
                              hipStream_t stream) {
  const float* x  = (const float*)d_in[0];
  const float* Wq = (const float*)d_in[1];
  const float* Wk = (const float*)d_in[2];
  const float* Wv = (const float*)d_in[3];
  const float* Wo = (const float*)d_in[4];
  const float* qg = (const float*)d_in[5];
  float* out = (float*)d_out;

  const size_t NE = (size_t)BH * S_ * DH;   // 8388608 elements
  const size_t WE = (size_t)DM * DM;        // 4194304 elements per W
  char* p = (char*)d_ws;
  float* q_ws = (float*)p; p += NE * 4;     // kpart1 during k-GEMM, then q
  float* k_ws = (float*)p; p += NE * 4;     // kpart0 -> roped k f32
  unsigned short* xhi = (unsigned short*)p; p += NE * 2;  // -> yf16 after k-GEMM
  unsigned short* xlo = (unsigned short*)p; p += NE * 2;  // -> vt after k-GEMM
  _Float16* xf16 = (_Float16*)p; p += NE * 2;
  unsigned short* wkhi = (unsigned short*)p; p += WE * 2; // -> kf16 after k-GEMM
  unsigned short* wklo = (unsigned short*)p; p += WE * 2;
  _Float16* wqv = (_Float16*)p; p += 2 * WE * 2;          // [Wq;Wv] fp16; -> wo
  float* cosb = (float*)p; p += (size_t)S_ * 64 * 4;
  float* sinb = (float*)p; p += (size_t)S_ * 64 * 4;
  float* projb = (float*)p; p += 4096 * 4;
  int* idxb = (int*)p; p += BH * NKEEP * 4;
  float* scores = (float*)p; p += BH * NBLK * 4;
  float* qpbuf = (float*)p; p += BH * 32 * 4;
  // aliases (stream-ordered safe):
  float* qpart = cosb;                 // rope tables dead after rmsrope_q
  float* kpart1 = q_ws;                // q_ws written by qv only AFTER rmsrope_k
  _Float16* kf16 = (_Float16*)wkhi;    // wk dead after k-GEMM; rmsrope_k writes
  _Float16* vt = (_Float16*)xlo;       // xlo dead after k-GEMM; qv writes after
  _Float16* yf16 = (_Float16*)xhi;     // xhi dead after k-GEMM; attn writes after
  _Float16* wo = wqv;                  // wqv dead after qv; Wo split after
  // total ws use ~152 MB (proven footprint, no growth)

  const int nx4 = (int)(NE / 4);
  const int nw4 = (int)(WE / 4);

  proj_kernel<<<dim3(16), dim3(256), 0, stream>>>(projb);
  rope_table_kernel<<<dim3(S_), dim3(64), 0, stream>>>(cosb, sinb);
  split_x3_kernel<<<dim3(nx4 / 256), dim3(256), 0, stream>>>(x, xhi, xlo, xf16, nx4);
  split_kernel<<<dim3(nw4 / 256), dim3(256), 0, stream>>>(Wk, wkhi, wklo, nw4);
  split_f16_kernel<<<dim3(nw4 / 256), dim3(256), 0, stream>>>(Wq, wqv, nw4);
  split_f16_kernel<<<dim3(nw4 / 256), dim3(256), 0, stream>>>(Wv, wqv + WE, nw4);

  // k: bf16x3, split-K=2, 8-wave 256^2, 4-phase counted-vmcnt interleave
  mfma_gemm_k_sk<<<dim3(8, 16, 2), dim3(512), 0, stream>>>(xhi, xlo, wkhi, wklo,
                                                           k_ws, kpart1);

  // k finalize: sum partials + RMS + RoPE; writes k f32 (in place) + kf16
  rmsrope_k_kernel<<<dim3((BH * S_) / 4), dim3(256), 0, stream>>>(k_ws, kpart1, kf16, cosb, sinb);

  // q+V fused: fp16, 256^2 8-wave, 2-phase; overwrites kpart1 (=q_ws) — safe now
  mfma_gemm_qv<<<dim3(16, 16), dim3(512), 0, stream>>>(xf16, wqv, q_ws, vt);

  rmsrope_q_kernel<<<dim3((BH * S_) / 4), dim3(256), 0, stream>>>(q_ws, cosb, sinb, qg);

  qmean_part_kernel<<<dim3(BH * 16), dim3(256), 0, stream>>>(q_ws, qpart);
  qproj_kernel<<<dim3(BH), dim3(128), 0, stream>>>(qpart, projb, qpbuf);
  kscore_kernel<<<dim3(BH * NBLK), dim3(256), 0, stream>>>(k_ws, projb, qpbuf, scores);
  topk_kernel<<<dim3(BH), dim3(64), 0, stream>>>(scores, idxb);

  // attn v5: 8-wave blocks (128 q rows), shared staging, defer-max
  attn_mfma_kernel<<<dim3(BH * 16), dim3(512), 0, stream>>>(q_ws, kf16, vt, idxb, yf16);

  // O: fp16 x1 on yf16 and Wo-f16
  split_f16_kernel<<<dim3(nw4 / 256), dim3(256), 0, stream>>>(Wo, wo, nw4);
  mfma_gemm_f16<1><<<dim3(16, 32), dim3(256), 0, stream>>>(yf16, wo, out);
}

// Round 15
// 446.564 us; speedup vs baseline: 1.0168x; 1.0168x over previous
//
#include <hip/hip_runtime.h>
#include <hip/hip_bf16.h>

#define B_ 2
#define S_ 2048
#define DM 2048
#define H_ 16
#define DH 128
#define NBLK 32
#define NKEEP 18
#define BH (B_ * H_)

typedef __attribute__((ext_vector_type(8))) short short8;
typedef __attribute__((ext_vector_type(8))) _Float16 f16x8;
typedef __attribute__((ext_vector_type(4))) _Float16 f16x4;
typedef __attribute__((ext_vector_type(4))) float f32x4;

#define GLOAD16(gp, lp)                                                        \
  __builtin_amdgcn_global_load_lds(                                            \
      (const __attribute__((address_space(1))) unsigned int*)(const void*)(gp),\
      (__attribute__((address_space(3))) unsigned int*)(void*)(lp), 16, 0, 0)

__device__ __forceinline__ unsigned short f32_to_bf16(float f) {
  unsigned u = __float_as_uint(f);
  unsigned r = (u + 0x7fffu + ((u >> 16) & 1u)) >> 16;
  return (unsigned short)r;
}
__device__ __forceinline__ float bf16_to_f32(unsigned short h) {
  return __uint_as_float(((unsigned)h) << 16);
}

// ---------------- proj: threefry2x32 (partitionable) + erfinv ----------------
__device__ __forceinline__ unsigned rotl32(unsigned x, int r) {
  return (x << r) | (x >> (32 - r));
}

__device__ __forceinline__ float erfinv_f32(float x) {
  float w = -log1pf(-x * x);
  float p;
  if (w < 5.0f) {
    w -= 2.5f;
    p = 2.81022636e-08f;
    p = fmaf(p, w, 3.43273939e-07f);
    p = fmaf(p, w, -3.5233877e-06f);
    p = fmaf(p, w, -4.39150654e-06f);
    p = fmaf(p, w, 0.00021858087f);
    p = fmaf(p, w, -0.00125372503f);
    p = fmaf(p, w, -0.00417768164f);
    p = fmaf(p, w, 0.246640727f);
    p = fmaf(p, w, 1.50140941f);
  } else {
    w = sqrtf(w) - 3.0f;
    p = -0.000200214257f;
    p = fmaf(p, w, 0.000100950558f);
    p = fmaf(p, w, 0.00134934322f);
    p = fmaf(p, w, -0.00367342844f);
    p = fmaf(p, w, 0.00573950773f);
    p = fmaf(p, w, -0.0076224613f);
    p = fmaf(p, w, 0.00943887047f);
    p = fmaf(p, w, 1.00167406f);
    p = fmaf(p, w, 2.83297682f);
  }
  return p * x;
}

__device__ __forceinline__ float bits_to_normal(unsigned b) {
  float f = __uint_as_float((b >> 9) | 0x3f800000u) - 1.0f;
  const float lo = -0.9999999403953552f;
  float u = fmaxf(lo, fmaf(f, 2.0f, lo));
  return 1.4142135623730951f * erfinv_f32(u);
}

__global__ void proj_kernel(float* __restrict__ proj) {
  int i = blockIdx.x * blockDim.x + threadIdx.x;
  if (i >= 4096) return;
  unsigned k0 = 0u, k1 = 42u;
  unsigned k2 = 0x1BD11BDAu ^ k0 ^ k1;
  unsigned x0 = 0u, x1 = (unsigned)i;
  x0 += k0; x1 += k1;
#define QR(r) { x0 += x1; x1 = rotl32(x1, r); x1 ^= x0; }
  QR(13) QR(15) QR(26) QR(6)   x0 += k1; x1 += k2 + 1u;
  QR(17) QR(29) QR(16) QR(24)  x0 += k2; x1 += k0 + 2u;
  QR(13) QR(15) QR(26) QR(6)   x0 += k0; x1 += k1 + 3u;
  QR(17) QR(29) QR(16) QR(24)  x0 += k1; x1 += k2 + 4u;
  QR(13) QR(15) QR(26) QR(6)   x0 += k2; x1 += k0 + 5u;
#undef QR
  proj[i] = bits_to_normal(x0 ^ x1) / 5.656854249492381f;
}

// ---------------- RoPE tables ----------------
__global__ void rope_table_kernel(float* __restrict__ cosb, float* __restrict__ sinb) {
  int s = blockIdx.x;
  int j = threadIdx.x;
  double e = (double)(2 * j) / 128.0;
  double invf = 1.0 / pow(10000.0, e);
  float freq = (float)s * (float)invf;
  cosb[s * 64 + j] = (float)cos((double)freq);
  sinb[s * 64 + j] = (float)sin((double)freq);
}

// ---------------- x -> bf16 hi/lo + fp16, single pass ----------------
__global__ __launch_bounds__(256) void split_x3_kernel(const float* __restrict__ in,
                                                       unsigned short* __restrict__ hi,
                                                       unsigned short* __restrict__ lo,
                                                       _Float16* __restrict__ f16,
                                                       int n4) {
  int i = blockIdx.x * blockDim.x + threadIdx.x;
  if (i >= n4) return;
  float4 v = ((const float4*)in)[i];
  ushort4 hv, lv;
  f16x4 fv;
  hv.x = f32_to_bf16(v.x); lv.x = f32_to_bf16(v.x - bf16_to_f32(hv.x)); fv[0] = (_Float16)v.x;
  hv.y = f32_to_bf16(v.y); lv.y = f32_to_bf16(v.y - bf16_to_f32(hv.y)); fv[1] = (_Float16)v.y;
  hv.z = f32_to_bf16(v.z); lv.z = f32_to_bf16(v.z - bf16_to_f32(hv.z)); fv[2] = (_Float16)v.z;
  hv.w = f32_to_bf16(v.w); lv.w = f32_to_bf16(v.w - bf16_to_f32(hv.w)); fv[3] = (_Float16)v.w;
  ((ushort4*)hi)[i] = hv;
  ((ushort4*)lo)[i] = lv;
  ((f16x4*)f16)[i] = fv;
}

// ---------------- fused W split: Wk -> bf16 hi/lo; Wq, Wv -> fp16 ----------
__global__ __launch_bounds__(256) void split_w3_kernel(const float* __restrict__ wk,
                                                       const float* __restrict__ wq,
                                                       const float* __restrict__ wv,
                                                       unsigned short* __restrict__ khi,
                                                       unsigned short* __restrict__ klo,
                                                       _Float16* __restrict__ qf,
                                                       _Float16* __restrict__ vf,
                                                       int n4) {
  int i = blockIdx.x * blockDim.x + threadIdx.x;
  if (i >= n4) return;
  {
    float4 v = ((const float4*)wk)[i];
    ushort4 hv, lv;
    hv.x = f32_to_bf16(v.x); lv.x = f32_to_bf16(v.x - bf16_to_f32(hv.x));
    hv.y = f32_to_bf16(v.y); lv.y = f32_to_bf16(v.y - bf16_to_f32(hv.y));
    hv.z = f32_to_bf16(v.z); lv.z = f32_to_bf16(v.z - bf16_to_f32(hv.z));
    hv.w = f32_to_bf16(v.w); lv.w = f32_to_bf16(v.w - bf16_to_f32(hv.w));
    ((ushort4*)khi)[i] = hv;
    ((ushort4*)klo)[i] = lv;
  }
  {
    float4 v = ((const float4*)wq)[i];
    f16x4 fv;
    fv[0] = (_Float16)v.x; fv[1] = (_Float16)v.y;
    fv[2] = (_Float16)v.z; fv[3] = (_Float16)v.w;
    ((f16x4*)qf)[i] = fv;
  }
  {
    float4 v = ((const float4*)wv)[i];
    f16x4 fv;
    fv[0] = (_Float16)v.x; fv[1] = (_Float16)v.y;
    fv[2] = (_Float16)v.z; fv[3] = (_Float16)v.w;
    ((f16x4*)vf)[i] = fv;
  }
}

// ---------------- W -> fp16 (Wo, late) ----------------
__global__ __launch_bounds__(256) void split_f16_kernel(const float* __restrict__ in,
                                                        _Float16* __restrict__ f16,
                                                        int n4) {
  int i = blockIdx.x * blockDim.x + threadIdx.x;
  if (i >= n4) return;
  float4 v = ((const float4*)in)[i];
  f16x4 fv;
  fv[0] = (_Float16)v.x; fv[1] = (_Float16)v.y;
  fv[2] = (_Float16)v.z; fv[3] = (_Float16)v.w;
  ((f16x4*)f16)[i] = fv;
}

// ---------------- k-GEMM: bf16x3, 256x256, 8 waves, SPLIT-K=2, 4-phase ------
__global__ __launch_bounds__(512, 2) void mfma_gemm_k_sk(const unsigned short* __restrict__ Ahi,
                                                         const unsigned short* __restrict__ Alo,
                                                         const unsigned short* __restrict__ Whi,
                                                         const unsigned short* __restrict__ Wlo,
                                                         float* __restrict__ kp0,
                                                         float* __restrict__ kp1) {
  __shared__ char smem[131072];  // 2 buf x 64K: Ahi 0|Alo 16K|Bhi 32K|Blo 48K
  const int t = threadIdx.x, l = t & 63, w = t >> 6;  // 8 waves
  const int lin = blockIdx.z * 128 + blockIdx.y * 8 + blockIdx.x;
  const int swz = (lin & 7) * 32 + (lin >> 3);        // 256 blocks, bijective
  const int kz = swz >> 7;
  const int idx = swz & 127;
  const int n0 = (idx & 7) * 256;
  const int m0 = (idx >> 3) * 256;
  const int kbase = kz * 1024;
  float* C = kz ? kp1 : kp0;
  const int wm = w >> 2, wn = w & 3;                  // 2M x 4N wave grid
  const int lr = l & 15;
  const int lg8 = (l >> 4) * 8;
  const size_t rstep = (size_t)16 * DM;

  const unsigned short* gAh = Ahi + (size_t)(m0 + w * 32 + lr) * DM + lg8;
  const unsigned short* gAl = Alo + (size_t)(m0 + w * 32 + lr) * DM + lg8;
  const unsigned short* gBh = Whi + (size_t)(n0 + w * 32 + lr) * DM + lg8;
  const unsigned short* gBl = Wlo + (size_t)(n0 + w * 32 + lr) * DM + lg8;

  f32x4 acc[8][4];
#pragma unroll
  for (int i = 0; i < 8; ++i)
#pragma unroll
    for (int j = 0; j < 4; ++j) acc[i][j] = (f32x4){0.f, 0.f, 0.f, 0.f};

  {  // prologue: full stage of tile 0 into buf 0
    char* base = smem + w * 2048;
    GLOAD16(gAh + kbase, base);
    GLOAD16(gAh + rstep + kbase, base + 1024);
    GLOAD16(gAl + kbase, base + 16384);
    GLOAD16(gAl + rstep + kbase, base + 16384 + 1024);
    GLOAD16(gBh + kbase, base + 32768);
    GLOAD16(gBh + rstep + kbase, base + 32768 + 1024);
    GLOAD16(gBl + kbase, base + 49152);
    GLOAD16(gBl + rstep + kbase, base + 49152 + 1024);
  }
  int cur = 0;

#define KQUAD(q)                                                                        \
  {                                                                                     \
    short8 ah0 = *(const short8*)(buf + (wm * 8 + 2 * (q)) * 1024 + l * 16);            \
    short8 ah1 = *(const short8*)(buf + (wm * 8 + 2 * (q) + 1) * 1024 + l * 16);        \
    short8 al0 = *(const short8*)(buf + 16384 + (wm * 8 + 2 * (q)) * 1024 + l * 16);    \
    short8 al1 = *(const short8*)(buf + 16384 + (wm * 8 + 2 * (q) + 1) * 1024 + l * 16);\
    __builtin_amdgcn_s_setprio(1);                                                      \
    _Pragma("unroll")                                                                   \
    for (int n = 0; n < 4; ++n) {                                                       \
      acc[2 * (q)][n] = __builtin_amdgcn_mfma_f32_16x16x32_bf16(ah0, bh[n], acc[2 * (q)][n], 0, 0, 0); \
      acc[2 * (q)][n] = __builtin_amdgcn_mfma_f32_16x16x32_bf16(ah0, bl[n], acc[2 * (q)][n], 0, 0, 0); \
      acc[2 * (q)][n] = __builtin_amdgcn_mfma_f32_16x16x32_bf16(al0, bh[n], acc[2 * (q)][n], 0, 0, 0); \
    }                                                                                   \
    _Pragma("unroll")                                                                   \
    for (int n = 0; n < 4; ++n) {                                                       \
      acc[2 * (q) + 1][n] = __builtin_amdgcn_mfma_f32_16x16x32_bf16(ah1, bh[n], acc[2 * (q) + 1][n], 0, 0, 0); \
      acc[2 * (q) + 1][n] = __builtin_amdgcn_mfma_f32_16x16x32_bf16(ah1, bl[n], acc[2 * (q) + 1][n], 0, 0, 0); \
      acc[2 * (q) + 1][n] = __builtin_amdgcn_mfma_f32_16x16x32_bf16(al1, bh[n], acc[2 * (q) + 1][n], 0, 0, 0); \
    }                                                                                   \
    __builtin_amdgcn_s_setprio(0);                                                      \
  }

  for (int k0 = kbase; k0 < kbase + 1024; k0 += 32) {
    const bool more = (k0 + 32 < kbase + 1024);
    char* buf = smem + cur * 65536;
    char* nb = smem + (cur ^ 1) * 65536 + w * 2048;
    const int kn = k0 + 32;

    if (more) {
      GLOAD16(gBh + kn, nb + 32768);
      GLOAD16(gBh + rstep + kn, nb + 32768 + 1024);
      asm volatile("s_waitcnt vmcnt(2)" ::: "memory");
    } else {
      asm volatile("s_waitcnt vmcnt(0)" ::: "memory");
    }
    __builtin_amdgcn_s_barrier();

    short8 bh[4], bl[4];
#pragma unroll
    for (int f = 0; f < 4; ++f) {
      bh[f] = *(const short8*)(buf + 32768 + (wn * 4 + f) * 1024 + l * 16);
      bl[f] = *(const short8*)(buf + 49152 + (wn * 4 + f) * 1024 + l * 16);
    }
    KQUAD(0);
    __builtin_amdgcn_s_barrier();

    if (more) {
      GLOAD16(gBl + kn, nb + 49152);
      GLOAD16(gBl + rstep + kn, nb + 49152 + 1024);
    }
    KQUAD(1);
    __builtin_amdgcn_s_barrier();

    if (more) {
      GLOAD16(gAh + kn, nb);
      GLOAD16(gAh + rstep + kn, nb + 1024);
    }
    KQUAD(2);
    __builtin_amdgcn_s_barrier();

    if (more) {
      GLOAD16(gAl + kn, nb + 16384);
      GLOAD16(gAl + rstep + kn, nb + 16384 + 1024);
    }
    KQUAD(3);
    __builtin_amdgcn_s_barrier();

    cur ^= 1;
  }
#undef KQUAD

#pragma unroll
  for (int m = 0; m < 8; ++m) {
    int row0 = m0 + wm * 128 + m * 16 + (l >> 4) * 4;
#pragma unroll
    for (int n = 0; n < 4; ++n) {
      int col = n0 + wn * 64 + n * 16 + (l & 15);
      int h = col >> 7, d = col & 127;
#pragma unroll
      for (int r = 0; r < 4; ++r) {
        int mm = row0 + r;
        int b = mm >> 11, s = mm & (S_ - 1);
        C[(((size_t)(b * H_ + h) * S_) + s) * DH + d] = acc[m][n][r];
      }
    }
  }
}

// ---------------- fused q+V fp16 GEMM: 256x256, 8 waves, 2-phase ------------
__global__ __launch_bounds__(512, 2) void mfma_gemm_qv(const _Float16* __restrict__ A,
                                                       const _Float16* __restrict__ W,
                                                       float* __restrict__ Cq,
                                                       _Float16* __restrict__ vt) {
  __shared__ char smem[65536];  // 2 buf x 32K: A frags 0..16K | B frags 16..32K
  const int t = threadIdx.x, l = t & 63, w = t >> 6;  // 8 waves
  const int lin = blockIdx.y * gridDim.x + blockIdx.x;
  const int swz = (lin & 7) * 32 + (lin >> 3);        // 256 blocks, bijective
  const int n0 = (swz & 15) * 256;
  const int m0 = (swz >> 4) * 256;
  const int wm = w >> 2, wn = w & 3;                  // 2M x 4N wave grid
  const int lr = l & 15;
  const int lg8 = (l >> 4) * 8;
  const size_t rstep = (size_t)16 * DM;

  const _Float16* gA = A + (size_t)(m0 + w * 32 + lr) * DM + lg8;
  const _Float16* gB = W + (size_t)(n0 + w * 32 + lr) * DM + lg8;

  f32x4 acc[8][4];
#pragma unroll
  for (int i = 0; i < 8; ++i)
#pragma unroll
    for (int j = 0; j < 4; ++j) acc[i][j] = (f32x4){0.f, 0.f, 0.f, 0.f};

  {  // prologue
    char* base = smem + w * 2048;
    GLOAD16(gA, base);
    GLOAD16(gA + rstep, base + 1024);
    GLOAD16(gB, base + 16384);
    GLOAD16(gB + rstep, base + 16384 + 1024);
  }
  int cur = 0;

  for (int k0 = 0; k0 < DM; k0 += 32) {
    const bool more = (k0 + 32 < DM);
    char* buf = smem + cur * 32768;
    char* nb = smem + (cur ^ 1) * 32768 + w * 2048;
    const int kn = k0 + 32;

    if (more) {
      GLOAD16(gA + kn, nb);
      GLOAD16(gA + rstep + kn, nb + 1024);
      asm volatile("s_waitcnt vmcnt(2)" ::: "memory");
    } else {
      asm volatile("s_waitcnt vmcnt(0)" ::: "memory");
    }
    __builtin_amdgcn_s_barrier();

    f16x8 b[4];
#pragma unroll
    for (int j = 0; j < 4; ++j)
      b[j] = *(const f16x8*)(buf + 16384 + (wn * 4 + j) * 1024 + l * 16);
    __builtin_amdgcn_s_setprio(1);
#pragma unroll
    for (int i = 0; i < 4; ++i) {
      f16x8 a = *(const f16x8*)(buf + (wm * 8 + i) * 1024 + l * 16);
#pragma unroll
      for (int j = 0; j < 4; ++j)
        acc[i][j] = __builtin_amdgcn_mfma_f32_16x16x32_f16(a, b[j], acc[i][j], 0, 0, 0);
    }
    __builtin_amdgcn_s_setprio(0);
    __builtin_amdgcn_s_barrier();

    if (more) {
      GLOAD16(gB + kn, nb + 16384);
      GLOAD16(gB + rstep + kn, nb + 16384 + 1024);
    }
    __builtin_amdgcn_s_setprio(1);
#pragma unroll
    for (int i = 4; i < 8; ++i) {
      f16x8 a = *(const f16x8*)(buf + (wm * 8 + i) * 1024 + l * 16);
#pragma unroll
      for (int j = 0; j < 4; ++j)
        acc[i][j] = __builtin_amdgcn_mfma_f32_16x16x32_f16(a, b[j], acc[i][j], 0, 0, 0);
    }
    __builtin_amdgcn_s_setprio(0);
    __builtin_amdgcn_s_barrier();

    cur ^= 1;
  }

#pragma unroll
  for (int m = 0; m < 8; ++m) {
    int row0 = m0 + wm * 128 + m * 16 + (l >> 4) * 4;
#pragma unroll
    for (int n = 0; n < 4; ++n) {
      int col = n0 + wn * 64 + n * 16 + (l & 15);
      if (col < DM) {
        int h = col >> 7, d = col & 127;
#pragma unroll
        for (int r = 0; r < 4; ++r) {
          int mm = row0 + r;
          int b2 = mm >> 11, s = mm & (S_ - 1);
          Cq[(((size_t)(b2 * H_ + h) * S_) + s) * DH + d] = acc[m][n][r];
        }
      } else {
        int vcol = col - DM;
        int h = vcol >> 7, d = vcol & 127;
        int b2 = row0 >> 11, s0 = row0 & (S_ - 1);
        f16x4 vv;
        vv[0] = (_Float16)acc[m][n][0];
        vv[1] = (_Float16)acc[m][n][1];
        vv[2] = (_Float16)acc[m][n][2];
        vv[3] = (_Float16)acc[m][n][3];
        *(f16x4*)(vt + (((size_t)(b2 * H_ + h)) * DH + d) * S_ + s0) = vv;
      }
    }
  }
}

// ---------------- fp16 single-product GEMM (O), BK=64, 128x128 --------------
template <int MODE>
__global__ __launch_bounds__(256) void mfma_gemm_f16(const _Float16* __restrict__ A,
                                                     const _Float16* __restrict__ W,
                                                     void* __restrict__ Cout) {
  __shared__ char smem[65536];
  const int t = threadIdx.x, l = t & 63, w = t >> 6;
  const int lin = blockIdx.y * gridDim.x + blockIdx.x;
  const int cpx = (gridDim.x * gridDim.y) >> 3;
  const int swz = (lin & 7) * cpx + (lin >> 3);
  const int n0 = (swz % gridDim.x) * 128;
  const int m0 = (swz / gridDim.x) * 128;
  const int wm = w >> 1, wn = w & 1;
  const int lr = l & 15;
  const int lg8 = (l >> 4) * 8;

  auto STAGE = [&](int k0, int c) {
    char* base = smem + c * 32768;
#pragma unroll
    for (int f0 = 0; f0 < 4; ++f0) {
      int f = w * 4 + f0;
      int rb = f >> 1, kh = f & 1;
      GLOAD16(A + (size_t)(m0 + rb * 16 + lr) * DM + k0 + kh * 32 + lg8,
              base + f * 1024);
      GLOAD16(W + (size_t)(n0 + rb * 16 + lr) * DM + k0 + kh * 32 + lg8,
              base + 16384 + f * 1024);
    }
  };

  f32x4 acc[4][4];
#pragma unroll
  for (int i = 0; i < 4; ++i)
#pragma unroll
    for (int j = 0; j < 4; ++j) acc[i][j] = (f32x4){0.f, 0.f, 0.f, 0.f};

  STAGE(0, 0);
  int cur = 0;

  for (int k0 = 0; k0 < DM; k0 += 64) {
    if (k0 + 64 < DM) {
      STAGE(k0 + 64, cur ^ 1);
      asm volatile("s_waitcnt vmcnt(8)" ::: "memory");
    } else {
      asm volatile("s_waitcnt vmcnt(0)" ::: "memory");
    }
    __builtin_amdgcn_s_barrier();

    char* buf = smem + cur * 32768;
    f16x8 a[4][2], b[4][2];
#pragma unroll
    for (int i = 0; i < 4; ++i)
#pragma unroll
      for (int kh = 0; kh < 2; ++kh) {
        a[i][kh] = *(const f16x8*)(buf + ((wm * 4 + i) * 2 + kh) * 1024 + l * 16);
        b[i][kh] = *(const f16x8*)(buf + 16384 + ((wn * 4 + i) * 2 + kh) * 1024 + l * 16);
      }
    __builtin_amdgcn_s_setprio(1);
#pragma unroll
    for (int i = 0; i < 4; ++i)
#pragma unroll
      for (int j = 0; j < 4; ++j) {
        acc[i][j] = __builtin_amdgcn_mfma_f32_16x16x32_f16(a[i][0], b[j][0], acc[i][j], 0, 0, 0);
        acc[i][j] = __builtin_amdgcn_mfma_f32_16x16x32_f16(a[i][1], b[j][1], acc[i][j], 0, 0, 0);
      }
    __builtin_amdgcn_s_setprio(0);
    __builtin_amdgcn_s_barrier();
    cur ^= 1;
  }

#pragma unroll
  for (int i = 0; i < 4; ++i) {
    int row0 = m0 + wm * 64 + i * 16 + (l >> 4) * 4;
#pragma unroll
    for (int j = 0; j < 4; ++j) {
      int col = n0 + wn * 64 + j * 16 + (l & 15);
      if constexpr (MODE == 1) {
        float* C = (float*)Cout;
#pragma unroll
        for (int r = 0; r < 4; ++r)
          C[(size_t)(row0 + r) * DM + col] = acc[i][j][r];
      }
    }
  }
}

// ---------------- RMSNorm + RoPE for K: sums split-K partials, emits fp16 ---
__global__ __launch_bounds__(256) void rmsrope_k_kernel(float* __restrict__ k,
                                                        const float* __restrict__ kp1,
                                                        _Float16* __restrict__ kf,
                                                        const float* __restrict__ cosb,
                                                        const float* __restrict__ sinb) {
  int w = threadIdx.x >> 6;
  int lane = threadIdx.x & 63;
  long r = (long)blockIdx.x * 4 + w;
  float* p = k + r * DH;
  const float* p1 = kp1 + r * DH;
  int s = (int)(r & (S_ - 1));
  float x1 = p[lane] + p1[lane];
  float x2 = p[lane + 64] + p1[lane + 64];
  float ss = fmaf(x1, x1, x2 * x2);
#pragma unroll
  for (int off = 32; off; off >>= 1) ss += __shfl_xor(ss, off);
  float rms = rsqrtf(ss * (1.0f / 128.0f) + 1e-6f);
  float n1 = x1 * rms, n2 = x2 * rms;
  float c = cosb[s * 64 + lane], sn = sinb[s * 64 + lane];
  float o1 = fmaf(n1, c, n2 * sn);
  float o2 = fmaf(-n1, sn, n2 * c);
  p[lane] = o1;
  p[lane + 64] = o2;
  kf[r * DH + lane] = (_Float16)o1;
  kf[r * DH + lane + 64] = (_Float16)o2;
}

// ---------------- RMSNorm + RoPE + gain for Q, in place ----------------
__global__ __launch_bounds__(256) void rmsrope_q_kernel(float* __restrict__ q,
                                                        const float* __restrict__ cosb,
                                                        const float* __restrict__ sinb,
                                                        const float* __restrict__ qg) {
  int w = threadIdx.x >> 6;
  int lane = threadIdx.x & 63;
  long r = (long)blockIdx.x * 4 + w;
  float* p = q + r * DH;
  int s = (int)(r & (S_ - 1));
  int h = (int)((r >> 11) & (H_ - 1));
  float x1 = p[lane], x2 = p[lane + 64];
  float ss = fmaf(x1, x1, x2 * x2);
#pragma unroll
  for (int off = 32; off; off >>= 1) ss += __shfl_xor(ss, off);
  float rms = rsqrtf(ss * (1.0f / 128.0f) + 1e-6f);
  float n1 = x1 * rms, n2 = x2 * rms;
  float c = cosb[s * 64 + lane], sn = sinb[s * 64 + lane];
  float g = qg[h];
  float o1 = fmaf(n1, c, n2 * sn) * g;
  float o2 = fmaf(-n1, sn, n2 * c) * g;
  p[lane] = o1;
  p[lane + 64] = o2;
}

// ---------------- selection phase 1: q-mean partial sums ----------------
__global__ __launch_bounds__(256) void qmean_part_kernel(const float* __restrict__ q,
                                                         float* __restrict__ partial) {
  __shared__ float red[256];
  const int bh = blockIdx.x >> 4, chunk = blockIdx.x & 15;
  const int t = threadIdx.x;
  const int d = t & 127, half = t >> 7;
  const float* qb = q + ((size_t)bh * S_ + chunk * 128 + half * 64) * DH;
  float sum = 0.0f;
#pragma unroll 4
  for (int s = 0; s < 64; ++s) sum += qb[(size_t)s * DH + d];
  red[t] = sum;
  __syncthreads();
  if (t < 128) partial[(size_t)blockIdx.x * 128 + t] = red[t] + red[t + 128];
}

// ---------------- selection phase 2: finish mean, project, normalize --------
__global__ void qproj_kernel(const float* __restrict__ partial,
                             const float* __restrict__ proj,
                             float* __restrict__ qp) {
  __shared__ float meanq[128];
  __shared__ float qps[32];
  __shared__ float nrm;
  const int bh = blockIdx.x, t = threadIdx.x;
  float s = 0.0f;
#pragma unroll
  for (int c = 0; c < 16; ++c) s += partial[((size_t)bh * 16 + c) * 128 + t];
  meanq[t] = s * (1.0f / 2048.0f);
  __syncthreads();
  if (t < 32) {
    float sum = 0.0f;
    for (int d = 0; d < 128; ++d) sum = fmaf(meanq[d], proj[d * 32 + t], sum);
    qps[t] = sum;
  }
  __syncthreads();
  if (t == 0) {
    float sum = 0.0f;
    for (int j = 0; j < 32; ++j) sum += qps[j] * qps[j];
    nrm = 1.0f / fmaxf(sqrtf(sum), 1e-12f);
  }
  __syncthreads();
  if (t < 32) qp[bh * 32 + t] = qps[t] * nrm;
}

// ---------------- selection phase 3: per-(bh,block) score ----------------
__global__ __launch_bounds__(256) void kscore_kernel(const float* __restrict__ k,
                                                     const float* __restrict__ proj,
                                                     const float* __restrict__ qp,
                                                     float* __restrict__ scores) {
  __shared__ float ps[128][32];
  __shared__ float kp[64][33];
  __shared__ float cent[33];
  __shared__ float nrm;
  const int bh = blockIdx.x >> 5, n = blockIdx.x & 31;
  const int t = threadIdx.x;
  for (int i = t; i < 4096; i += 256) ps[i >> 5][i & 31] = proj[i];
  const float* kn = k + ((size_t)bh * S_ + n * 64) * DH;
  __syncthreads();
  {
    int row = t >> 2, j0 = (t & 3) * 8;
    float accv[8];
#pragma unroll
    for (int jj = 0; jj < 8; ++jj) accv[jj] = 0.0f;
#pragma unroll 4
    for (int d = 0; d < 128; ++d) {
      float kv = kn[(size_t)row * DH + d];
#pragma unroll
      for (int jj = 0; jj < 8; ++jj) accv[jj] = fmaf(kv, ps[d][j0 + jj], accv[jj]);
    }
#pragma unroll
    for (int jj = 0; jj < 8; ++jj) kp[row][j0 + jj] = accv[jj];
  }
  __syncthreads();
  if (t < 64) {
    float sum = 0.0f;
    for (int j = 0; j < 32; ++j) sum += kp[t][j] * kp[t][j];
    float scl = 1.0f / fmaxf(sqrtf(sum), 1e-12f);
    for (int j = 0; j < 32; ++j) kp[t][j] *= scl;
  }
  __syncthreads();
  if (t < 32) {
    float sum = 0.0f;
    for (int r2 = 0; r2 < 64; ++r2) sum += kp[r2][t];
    cent[t] = sum * (1.0f / 64.0f);
  }
  __syncthreads();
  if (t == 0) {
    float sum = 0.0f;
    for (int j = 0; j < 32; ++j) sum += cent[j] * cent[j];
    nrm = 1.0f / fmaxf(sqrtf(sum), 1e-12f);
  }
  __syncthreads();
  if (t < 32) cent[t] *= nrm;
  __syncthreads();
  if (t < 64) {
    float dt = 0.0f;
    for (int j = 0; j < 32; ++j) dt = fmaf(kp[t][j], cent[j], dt);
#pragma unroll
    for (int off = 32; off; off >>= 1) dt = fminf(dt, __shfl_xor(dt, off));
    if (t == 0) {
      float radius = fminf(fmaxf(1.0f - dt, 0.0f), 1.0f);
      float dq = 0.0f;
      for (int j = 0; j < 32; ++j) dq = fmaf(qp[bh * 32 + j], cent[j], dq);
      scores[bh * 32 + n] = dq + radius;
    }
  }
}

// ---------------- selection phase 4: top-18 + sort ----------------
__global__ void topk_kernel(const float* __restrict__ scores, int* __restrict__ top_idx) {
  if (threadIdx.x != 0) return;
  const int bh = blockIdx.x;
  float sc[NBLK];
  for (int j = 0; j < NBLK; ++j) sc[j] = scores[bh * 32 + j];
  sc[NBLK - 2] = INFINITY;
  sc[NBLK - 1] = INFINITY;
  int chosen[NKEEP];
  bool used[NBLK];
  for (int j = 0; j < NBLK; ++j) used[j] = false;
  for (int kk = 0; kk < NKEEP; ++kk) {
    int best = -1;
    float bv = 0.0f;
    for (int j = 0; j < NBLK; ++j)
      if (!used[j] && (best < 0 || sc[j] > bv)) { bv = sc[j]; best = j; }
    used[best] = true;
    chosen[kk] = best;
  }
  for (int a = 1; a < NKEEP; ++a) {
    int v2 = chosen[a], b2 = a - 1;
    while (b2 >= 0 && chosen[b2] > v2) { chosen[b2 + 1] = chosen[b2]; --b2; }
    chosen[b2 + 1] = v2;
  }
  for (int a = 0; a < NKEEP; ++a) top_idx[bh * NKEEP + a] = chosen[a];
}

// ---------------- MFMA attention v6: R13 geometry (4 waves/64 q) + defer-max
__global__ __launch_bounds__(256) void attn_mfma_kernel(const float* __restrict__ q,
                                                        const _Float16* __restrict__ kf,
                                                        const _Float16* __restrict__ vt,
                                                        const int* __restrict__ top_idx,
                                                        _Float16* __restrict__ yf) {
  __shared__ char lds[74752];  // buf0 0..32K (K 16K|V 16K), buf1 32..64K, P 64K..
  const int bh = blockIdx.x >> 5;
  const int qt = blockIdx.x & 31;
  const int t = threadIdx.x, l = t & 63, w = t >> 6;
  const int lr = l & 15, lg = l >> 4;
  const float scale = 0.08838834764831843f;  // 1/sqrt(128)

  f16x8 qf[4];
  {
    const float* qbase = q + ((size_t)(bh * S_ + qt * 64 + w * 16 + lr)) * DH + lg * 8;
#pragma unroll
    for (int dc = 0; dc < 4; ++dc) {
      float4 v0 = *(const float4*)(qbase + dc * 32);
      float4 v1 = *(const float4*)(qbase + dc * 32 + 4);
      f16x8 h;
      h[0] = (_Float16)v0.x; h[1] = (_Float16)v0.y; h[2] = (_Float16)v0.z; h[3] = (_Float16)v0.w;
      h[4] = (_Float16)v1.x; h[5] = (_Float16)v1.y; h[6] = (_Float16)v1.z; h[7] = (_Float16)v1.w;
      qf[dc] = h;
    }
  }

  float m_[4] = {-INFINITY, -INFINITY, -INFINITY, -INFINITY};
  float ls[4] = {0.f, 0.f, 0.f, 0.f};
  f32x4 yacc[8];
#pragma unroll
  for (int dt = 0; dt < 8; ++dt) yacc[dt] = (f32x4){0.f, 0.f, 0.f, 0.f};

  char* Pw = lds + 65536 + w * 2304;  // per-wave P: [16 q][72 fp16]

  const _Float16* kb0 = kf + (size_t)bh * S_ * DH;
  const _Float16* vb0 = vt + (size_t)bh * DH * S_;
  const int* idxp = top_idx + bh * NKEEP;

  auto STAGE = [&](int blk, int c) {
    char* base = lds + c * 32768;
#pragma unroll
    for (int f0 = 0; f0 < 4; ++f0) {
      int f = w * 4 + f0;
      int kt = f >> 2, dc = f & 3;
      GLOAD16(kb0 + (size_t)(blk * 64 + kt * 16 + lr) * DH + dc * 32 + lg * 8,
              base + f * 1024);
      int K0 = f >> 3, dt = f & 7;
      GLOAD16(vb0 + (size_t)(dt * 16 + lr) * S_ + blk * 64 + K0 * 32 + lg * 8,
              base + 16384 + f * 1024);
    }
  };

  int cur = 0;
  STAGE(idxp[0], 0);

  for (int it = 0; it < NKEEP; ++it) {
    if (it + 1 < NKEEP) {
      STAGE(idxp[it + 1], cur ^ 1);
      asm volatile("s_waitcnt vmcnt(8)" ::: "memory");
    } else {
      asm volatile("s_waitcnt vmcnt(0)" ::: "memory");
    }
    __builtin_amdgcn_s_barrier();
    char* buf = lds + cur * 32768;

    f32x4 sacc[4];
#pragma unroll
    for (int kt = 0; kt < 4; ++kt) sacc[kt] = (f32x4){0.f, 0.f, 0.f, 0.f};
    __builtin_amdgcn_s_setprio(1);
#pragma unroll
    for (int kt = 0; kt < 4; ++kt)
#pragma unroll
      for (int dc = 0; dc < 4; ++dc) {
        f16x8 kfr = *(const f16x8*)(buf + (kt * 4 + dc) * 1024 + l * 16);
        sacc[kt] = __builtin_amdgcn_mfma_f32_16x16x32_f16(qf[dc], kfr, sacc[kt], 0, 0, 0);
      }
    __builtin_amdgcn_s_setprio(0);

    // per-row tile max (reduced over the row's 16 lanes)
    float mt[4];
#pragma unroll
    for (int r = 0; r < 4; ++r) {
      float mv = fmaxf(fmaxf(sacc[0][r], sacc[1][r]), fmaxf(sacc[2][r], sacc[3][r])) * scale;
#pragma unroll
      for (int off = 1; off < 16; off <<= 1) mv = fmaxf(mv, __shfl_xor(mv, off));
      mt[r] = mv;
    }
    float p[4][4];
    bool ok = (mt[0] <= m_[0] + 8.0f) && (mt[1] <= m_[1] + 8.0f) &&
              (mt[2] <= m_[2] + 8.0f) && (mt[3] <= m_[3] + 8.0f);
    if (__all(ok)) {
      // defer-max (T13): keep old max, skip corr/rescale (P bounded by e^8)
#pragma unroll
      for (int r = 0; r < 4; ++r) {
        float rs = 0.f;
#pragma unroll
        for (int kt = 0; kt < 4; ++kt) {
          p[kt][r] = __expf(fmaf(sacc[kt][r], scale, -m_[r]));
          rs += p[kt][r];
        }
#pragma unroll
        for (int off = 1; off < 16; off <<= 1) rs += __shfl_xor(rs, off);
        ls[r] += rs;
      }
    } else {
#pragma unroll
      for (int r = 0; r < 4; ++r) {
        float mn = fmaxf(m_[r], mt[r]);
        float corr = __expf(m_[r] - mn);
        float rs = 0.f;
#pragma unroll
        for (int kt = 0; kt < 4; ++kt) {
          p[kt][r] = __expf(fmaf(sacc[kt][r], scale, -mn));
          rs += p[kt][r];
        }
#pragma unroll
        for (int off = 1; off < 16; off <<= 1) rs += __shfl_xor(rs, off);
        ls[r] = ls[r] * corr + rs;
        m_[r] = mn;
#pragma unroll
        for (int dt = 0; dt < 8; ++dt) yacc[dt][r] *= corr;
      }
    }

#pragma unroll
    for (int kt = 0; kt < 4; ++kt)
#pragma unroll
      for (int r = 0; r < 4; ++r)
        *(_Float16*)(Pw + (lg * 4 + r) * 144 + (kt * 16 + lr) * 2) = (_Float16)p[kt][r];

    __builtin_amdgcn_s_setprio(1);
#pragma unroll
    for (int K0 = 0; K0 < 2; ++K0) {
      f16x8 pa = *(const f16x8*)(Pw + lr * 144 + K0 * 64 + lg * 16);
#pragma unroll
      for (int dt = 0; dt < 8; ++dt) {
        f16x8 vf = *(const f16x8*)(buf + 16384 + (K0 * 8 + dt) * 1024 + l * 16);
        yacc[dt] = __builtin_amdgcn_mfma_f32_16x16x32_f16(pa, vf, yacc[dt], 0, 0, 0);
      }
    }
    __builtin_amdgcn_s_setprio(0);

    __builtin_amdgcn_s_barrier();
    cur ^= 1;
  }

  const int b = bh >> 4, h = bh & (H_ - 1);
  float inv[4];
#pragma unroll
  for (int r = 0; r < 4; ++r) inv[r] = 1.0f / ls[r];
#pragma unroll
  for (int r = 0; r < 4; ++r) {
    int srow = qt * 64 + w * 16 + lg * 4 + r;
    size_t off0 = ((size_t)b * S_ + srow) * DM + h * DH + lr;
#pragma unroll
    for (int dt = 0; dt < 8; ++dt)
      yf[off0 + dt * 16] = (_Float16)(yacc[dt][r] * inv[r]);
  }
}

extern "C" void kernel_launch(void* const* d_in, const int* in_sizes, int n_in,
                              void* d_out, int out_size, void* d_ws, size_t ws_size,
                              hipStream_t stream) {
  const float* x  = (const float*)d_in[0];
  const float* Wq = (const float*)d_in[1];
  const float* Wk = (const float*)d_in[2];
  const float* Wv = (const float*)d_in[3];
  const float* Wo = (const float*)d_in[4];
  const float* qg = (const float*)d_in[5];
  float* out = (float*)d_out;

  const size_t NE = (size_t)BH * S_ * DH;   // 8388608 elements
  const size_t WE = (size_t)DM * DM;        // 4194304 elements per W
  char* p = (char*)d_ws;
  float* q_ws = (float*)p; p += NE * 4;     // kpart1 during k-GEMM, then q
  float* k_ws = (float*)p; p += NE * 4;     // kpart0 -> roped k f32
  unsigned short* xhi = (unsigned short*)p; p += NE * 2;  // -> yf16 after k-GEMM
  unsigned short* xlo = (unsigned short*)p; p += NE * 2;  // -> vt after k-GEMM
  _Float16* xf16 = (_Float16*)p; p += NE * 2;
  unsigned short* wkhi = (unsigned short*)p; p += WE * 2; // -> kf16 after k-GEMM
  unsigned short* wklo = (unsigned short*)p; p += WE * 2;
  _Float16* wqv = (_Float16*)p; p += 2 * WE * 2;          // [Wq;Wv] fp16; -> wo
  float* cosb = (float*)p; p += (size_t)S_ * 64 * 4;
  float* sinb = (float*)p; p += (size_t)S_ * 64 * 4;
  float* projb = (float*)p; p += 4096 * 4;
  int* idxb = (int*)p; p += BH * NKEEP * 4;
  float* scores = (float*)p; p += BH * NBLK * 4;
  float* qpbuf = (float*)p; p += BH * 32 * 4;
  // aliases (stream-ordered safe):
  float* qpart = cosb;                 // rope tables dead after rmsrope_q
  float* kpart1 = q_ws;                // q_ws written by qv only AFTER rmsrope_k
  _Float16* kf16 = (_Float16*)wkhi;    // wk dead after k-GEMM; rmsrope_k writes
  _Float16* vt = (_Float16*)xlo;       // xlo dead after k-GEMM; qv writes after
  _Float16* yf16 = (_Float16*)xhi;     // xhi dead after k-GEMM; attn writes after
  _Float16* wo = wqv;                  // wqv dead after qv; Wo split after
  // total ws use ~152 MB (proven footprint, no growth)

  const int nx4 = (int)(NE / 4);
  const int nw4 = (int)(WE / 4);

  proj_kernel<<<dim3(16), dim3(256), 0, stream>>>(projb);
  rope_table_kernel<<<dim3(S_), dim3(64), 0, stream>>>(cosb, sinb);
  split_x3_kernel<<<dim3(nx4 / 256), dim3(256), 0, stream>>>(x, xhi, xlo, xf16, nx4);
  split_w3_kernel<<<dim3(nw4 / 256), dim3(256), 0, stream>>>(Wk, Wq, Wv, wkhi, wklo,
                                                             wqv, wqv + WE, nw4);

  // k: bf16x3, split-K=2, 8-wave 256^2, 4-phase counted-vmcnt interleave
  mfma_gemm_k_sk<<<dim3(8, 16, 2), dim3(512), 0, stream>>>(xhi, xlo, wkhi, wklo,
                                                           k_ws, kpart1);

  // k finalize: sum partials + RMS + RoPE; writes k f32 (in place) + kf16
  rmsrope_k_kernel<<<dim3((BH * S_) / 4), dim3(256), 0, stream>>>(k_ws, kpart1, kf16, cosb, sinb);

  // q+V fused: fp16, 256^2 8-wave, 2-phase; overwrites kpart1 (=q_ws) — safe now
  mfma_gemm_qv<<<dim3(16, 16), dim3(512), 0, stream>>>(xf16, wqv, q_ws, vt);

  rmsrope_q_kernel<<<dim3((BH * S_) / 4), dim3(256), 0, stream>>>(q_ws, cosb, sinb, qg);

  qmean_part_kernel<<<dim3(BH * 16), dim3(256), 0, stream>>>(q_ws, qpart);
  qproj_kernel<<<dim3(BH), dim3(128), 0, stream>>>(qpart, projb, qpbuf);
  kscore_kernel<<<dim3(BH * NBLK), dim3(256), 0, stream>>>(k_ws, projb, qpbuf, scores);
  topk_kernel<<<dim3(BH), dim3(64), 0, stream>>>(scores, idxb);

  // attn v6: 4-wave blocks (64 q rows, 2 blocks/CU), defer-max
  attn_mfma_kernel<<<dim3(BH * 32), dim3(256), 0, stream>>>(q_ws, kf16, vt, idxb, yf16);

  // O: fp16 x1 on yf16 and Wo-f16
  split_f16_kernel<<<dim3(nw4 / 256), dim3(256), 0, stream>>>(Wo, wo, nw4);
  mfma_gemm_f16<1><<<dim3(16, 32), dim3(256), 0, stream>>>(yf16, wo, out);
}